// Round 7
// baseline (114.209 us; speedup 1.0000x reference)
//
#include <hip/hip_runtime.h>
#include <hip/hip_bf16.h>

#define D 128
#define MARGIN 0.5f
#define NSPLIT 16      // j-splits; block j-window = 8192/16 = 512 cols
#define NC 100         // label classes

typedef __attribute__((ext_vector_type(8))) short bf16x8;
typedef __attribute__((ext_vector_type(4))) float f32x4;

// ---------------- sort pipeline: zero -> hist -> scan -> scatter ----------
__global__ void zero_kernel(int* __restrict__ hist, float* __restrict__ out) {
    if (threadIdx.x < NC) hist[threadIdx.x] = 0;
    if (threadIdx.x == 0) *out = 0.0f;
}

__global__ void hist_kernel(const int* __restrict__ tgt, int* __restrict__ hist, int n) {
    int i = blockIdx.x * blockDim.x + threadIdx.x;
    if (i < n) atomicAdd(&hist[tgt[i]], 1);
}

__global__ void scan_kernel(const int* __restrict__ hist,
                            int* __restrict__ starts,
                            int* __restrict__ ends,
                            int* __restrict__ cursor) {
    if (threadIdx.x == 0) {
        int acc = 0;
        for (int c = 0; c < NC; ++c) {
            starts[c] = acc;
            cursor[c] = acc;
            acc += hist[c];
            ends[c] = acc;
        }
    }
}

__global__ void scatter_kernel(const int* __restrict__ tgt,
                               int* __restrict__ cursor,
                               int* __restrict__ perm,
                               int* __restrict__ stgt, int n) {
    int i = blockIdx.x * blockDim.x + threadIdx.x;
    if (i < n) {
        int c = tgt[i];
        int p = atomicAdd(&cursor[c], 1);
        perm[p] = i;
        stgt[p] = c;
    }
}

// ---------------- pack: gather sorted rows, bf16 convert + sq + init ------
__global__ void pack_kernel(const float* __restrict__ x,
                            const int* __restrict__ perm,
                            float* __restrict__ sq,
                            unsigned* __restrict__ ap,
                            unsigned* __restrict__ an,
                            __hip_bfloat16* __restrict__ xb, int n) {
    int tid = threadIdx.x;
    int row = blockIdx.x * 4 + (tid >> 6);   // sorted row
    int lane = tid & 63;
    int orig = perm[row];
    const float2* xr = (const float2*)(x + (size_t)orig * D);
    float2 v = xr[lane];
    __hip_bfloat162 b2;
    b2.x = __float2bfloat16(v.x);
    b2.y = __float2bfloat16(v.y);
    ((__hip_bfloat162*)(xb + (size_t)row * D))[lane] = b2;
    float s = v.x * v.x + v.y * v.y;
    #pragma unroll
    for (int o = 32; o > 0; o >>= 1) s += __shfl_xor(s, o, 64);
    if (lane == 0) {
        sq[row] = s;
        ap[row] = 0u;            // dist >= 0 -> 0 is a valid -inf for max
        an[row] = 0x7F800000u;   // +inf bits
    }
}

// ---------------- gram: async B staging + sorted fast/slow tile paths -----
// Rows label-sorted: block's positive cols form one union [u0,u1). Tiles
// outside it take the 2-op/elem pure-negative path (~95%); intersecting
// tiles take the full masked path. Branch is block-uniform (scalar).
__launch_bounds__(256, 4)
__global__ void gram_kernel(const __hip_bfloat16* __restrict__ xb,
                            const float* __restrict__ sq,
                            const int* __restrict__ stgt,
                            const int* __restrict__ starts,
                            const int* __restrict__ ends,
                            unsigned* __restrict__ ap,
                            unsigned* __restrict__ an, int n) {
    __shared__ __align__(16) __hip_bfloat16 Bs[2][64 * D];

    const int tid  = threadIdx.x;
    const int wid  = tid >> 6;
    const int lane = tid & 63;
    const int quad = lane >> 4;
    const int l    = lane & 15;
    const int i0   = blockIdx.x * 128;
    const int jspan = n / NSPLIT;          // 512
    const int njit  = jspan / 64;          // 8
    const int j0    = blockIdx.y * jspan;
    const int rowbase = i0 + wid * 32;

    // block positive-column union (uniform)
    const int u0 = starts[stgt[i0]];
    const int u1 = ends[stgt[i0 + 127]];

    // A fragments, register-resident: lane holds A[m=l][k=quad*8+j]
    bf16x8 afrag[2][4];
    {
        const __hip_bfloat16* abase = xb + (size_t)(rowbase + l) * D + quad * 8;
        #pragma unroll
        for (int mt = 0; mt < 2; ++mt)
            #pragma unroll
            for (int ks = 0; ks < 4; ++ks)
                afrag[mt][ks] = *(const bf16x8*)(abase + (size_t)mt * 16 * D + ks * 32);
    }

    int li[2][4];
    #pragma unroll
    for (int mt = 0; mt < 2; ++mt)
        #pragma unroll
        for (int reg = 0; reg < 4; ++reg)
            li[mt][reg] = stgt[rowbase + mt * 16 + quad * 4 + reg];

    float lap[8], lan[8];
    #pragma unroll
    for (int k = 0; k < 8; ++k) { lap[k] = -1e30f; lan[k] = 1e30f; }

    const int q0 = wid * 256;
    const char* xbb = (const char*)xb;

    #define PREFETCH(jt0, buf)                                                \
        do {                                                                  \
            _Pragma("unroll")                                                 \
            for (int i_ = 0; i_ < 4; ++i_) {                                  \
                int q_ = q0 + i_ * 64 + lane;                                 \
                int r_ = q_ >> 4;                                             \
                int c_ = (q_ & 15) ^ (r_ & 15);                               \
                const char* g_ = xbb + (size_t)((jt0) + r_) * 256             \
                                     + (size_t)c_ * 16;                       \
                char* l_ = (char*)&Bs[buf][0] + (size_t)(q0 + i_ * 64) * 16;  \
                __builtin_amdgcn_global_load_lds(                             \
                    (const __attribute__((address_space(1))) void*)g_,        \
                    (__attribute__((address_space(3))) void*)l_, 16, 0, 0);   \
            }                                                                 \
        } while (0)

    PREFETCH(j0, 0);
    __syncthreads();

    for (int jj = 0; jj < njit; ++jj) {
        const int cur = jj & 1;
        if (jj < njit - 1) PREFETCH(j0 + (jj + 1) * 64, cur ^ 1);  // async

        const char* Bb = (const char*)&Bs[cur][0];
        const int jbase = j0 + jj * 64;
        const bool mixed = (jbase < u1) && (jbase + 64 > u0);   // uniform

        #pragma unroll
        for (int jt = 0; jt < 4; ++jt) {
            f32x4 acc0 = (f32x4){0.f, 0.f, 0.f, 0.f};
            f32x4 acc1 = (f32x4){0.f, 0.f, 0.f, 0.f};
            #pragma unroll
            for (int ks = 0; ks < 4; ++ks) {
                int q = (jt * 16 + l) * 16 + ((ks * 4 + quad) ^ l);
                bf16x8 bfr = *(const bf16x8*)(Bb + (size_t)q * 16);
                acc0 = __builtin_amdgcn_mfma_f32_16x16x32_bf16(afrag[0][ks], bfr, acc0, 0, 0, 0);
                acc1 = __builtin_amdgcn_mfma_f32_16x16x32_bf16(afrag[1][ks], bfr, acc1, 0, 0, 0);
            }
            float sjc = sq[jbase + jt * 16 + l];
            if (mixed) {
                int tjc = stgt[jbase + jt * 16 + l];
                #pragma unroll
                for (int reg = 0; reg < 4; ++reg) {
                    float t0 = fmaf(-2.0f, acc0[reg], sjc);
                    float t1 = fmaf(-2.0f, acc1[reg], sjc);
                    bool s0 = (li[0][reg] == tjc);
                    bool s1 = (li[1][reg] == tjc);
                    lap[reg]     = fmaxf(lap[reg],     s0 ? t0 : -1e30f);
                    lan[reg]     = fminf(lan[reg],     s0 ? 1e30f : t0);
                    lap[4 + reg] = fmaxf(lap[4 + reg], s1 ? t1 : -1e30f);
                    lan[4 + reg] = fminf(lan[4 + reg], s1 ? 1e30f : t1);
                }
            } else {
                // pure-negative tile: 2 ops/element
                #pragma unroll
                for (int reg = 0; reg < 4; ++reg) {
                    float t0 = fmaf(-2.0f, acc0[reg], sjc);
                    float t1 = fmaf(-2.0f, acc1[reg], sjc);
                    lan[reg]     = fminf(lan[reg],     t0);
                    lan[4 + reg] = fminf(lan[4 + reg], t1);
                }
            }
        }
        __syncthreads();
    }
    #undef PREFETCH

    // reduce across 16 column-lanes (xor<16 stays within quad group)
    #pragma unroll
    for (int mt = 0; mt < 2; ++mt)
        #pragma unroll
        for (int reg = 0; reg < 4; ++reg) {
            float p = lap[mt * 4 + reg], q = lan[mt * 4 + reg];
            #pragma unroll
            for (int o = 1; o < 16; o <<= 1) {
                p = fmaxf(p, __shfl_xor(p, o, 64));
                q = fminf(q, __shfl_xor(q, o, 64));
            }
            if (l == mt * 4 + reg) {   // one writer lane per quad
                int gi = rowbase + mt * 16 + quad * 4 + reg;
                float s = sq[gi];
                atomicMax(&ap[gi], __float_as_uint(fmaxf(s + p, 0.0f)));
                atomicMin(&an[gi], __float_as_uint(fmaxf(s + q, 0.0f)));
            }
        }
}

// ---------------- final: sum relu(ap - an + margin) ----------------
__global__ void final_kernel(const unsigned* __restrict__ ap,
                             const unsigned* __restrict__ an,
                             float* __restrict__ out, int n) {
    int i = blockIdx.x * blockDim.x + threadIdx.x;
    float v = 0.f;
    if (i < n) {
        float p = __uint_as_float(ap[i]);
        float q = __uint_as_float(an[i]);
        v = fmaxf(p - q + MARGIN, 0.0f);
    }
    #pragma unroll
    for (int o = 32; o > 0; o >>= 1) v += __shfl_xor(v, o, 64);
    __shared__ float ws[4];
    int lane = threadIdx.x & 63, w = threadIdx.x >> 6;
    if (lane == 0) ws[w] = v;
    __syncthreads();
    if (threadIdx.x == 0) atomicAdd(out, ws[0] + ws[1] + ws[2] + ws[3]);
}

extern "C" void kernel_launch(void* const* d_in, const int* in_sizes, int n_in,
                              void* d_out, int out_size, void* d_ws, size_t ws_size,
                              hipStream_t stream) {
    const float* x   = (const float*)d_in[0];
    const int*   tgt = (const int*)d_in[1];
    float* out = (float*)d_out;
    const int n = in_sizes[1];              // 8192

    char* w = (char*)d_ws;
    float*          sq     = (float*)w;                  w += (size_t)n * 4;
    unsigned*       ap     = (unsigned*)w;               w += (size_t)n * 4;
    unsigned*       an     = (unsigned*)w;               w += (size_t)n * 4;
    int*            perm   = (int*)w;                    w += (size_t)n * 4;
    int*            stgt   = (int*)w;                    w += (size_t)n * 4;
    int*            hist   = (int*)w;                    w += 256 * 4;
    int*            starts = (int*)w;                    w += 256 * 4;
    int*            ends   = (int*)w;                    w += 256 * 4;
    int*            cursor = (int*)w;                    w += 256 * 4;
    __hip_bfloat16* xb     = (__hip_bfloat16*)w;

    zero_kernel<<<1, 256, 0, stream>>>(hist, out);
    hist_kernel<<<n / 256, 256, 0, stream>>>(tgt, hist, n);
    scan_kernel<<<1, 64, 0, stream>>>(hist, starts, ends, cursor);
    scatter_kernel<<<n / 256, 256, 0, stream>>>(tgt, cursor, perm, stgt, n);
    pack_kernel<<<n / 4, 256, 0, stream>>>(x, perm, sq, ap, an, xb, n);
    dim3 grid(n / 128, NSPLIT);
    gram_kernel<<<grid, 256, 0, stream>>>(xb, sq, stgt, starts, ends, ap, an, n);
    final_kernel<<<n / 256, 256, 0, stream>>>(ap, an, out, n);
}